// Round 11
// baseline (100.765 us; speedup 1.0000x reference)
//
#include <hip/hip_runtime.h>
#include <hip/hip_bf16.h>
#include <hip/hip_fp16.h>

typedef _Float16 f16;
typedef __attribute__((ext_vector_type(8))) _Float16 f16x8;
typedef __attribute__((ext_vector_type(4))) float f32x4;

#define DIM     2048
#define BROWS   8192
#define NCOLS   1221      // 111 nodes * 11
#define NPAD    1280      // 10 panels of 128
#define NNODES  111
#define BK      64
#define NKT     32
#define IMG     8192          // f16 per (128-panel, kt) fragment image (16 KB)
#define PANEL   (32 * IMG)
// Fragment image per (128-panel, kt): 1024 chunks x 16B.
// chunk c = (kk*8 + g)*64 + l ; lane l (r=l&15,q=l>>4) holds
//   row/col = g*16 + r , k = kk*32 + q*8 .. +8.

// ---------------------------------------------------------------------------
// prep_all: block < 2048 -> prep_x (x f32 -> Xf fragment f16)
//           block >= 2048 -> prep_b (W f32 -> Bf fragment f16)
// ---------------------------------------------------------------------------
__global__ __launch_bounds__(256) void prep_all(const float* __restrict__ X,
                                                const float* __restrict__ W,
                                                f16* __restrict__ Xf,
                                                f16* __restrict__ Bf) {
    __shared__ float T[128 * 68];
    int b = blockIdx.x;
    if (b < 2048) {
        int mp = b >> 5, kt = b & 31;
        int t = threadIdx.x;
        int row = t >> 1, half = t & 1;
        const float* src = X + (size_t)(mp * 128 + row) * DIM + kt * 64 + half * 32;
        float* dst = T + row * 68 + half * 32;
        #pragma unroll
        for (int i = 0; i < 8; ++i) ((f32x4*)dst)[i] = ((const f32x4*)src)[i];
        __syncthreads();
        int w = t >> 6, l = t & 63, r = l & 15, q = l >> 4;
        f16* out = Xf + (size_t)b * IMG;
        #pragma unroll
        for (int p = 0; p < 4; ++p) {
            int gk = p * 4 + w;                // = kk*8 + g
            int kk = gk >> 3, g = gk & 7;
            const float* s = T + (g * 16 + r) * 68 + kk * 32 + q * 8;
            f32x4 a = *(const f32x4*)s;
            f32x4 c = *(const f32x4*)(s + 4);
            f16x8 h;
            h[0] = (f16)a[0]; h[1] = (f16)a[1]; h[2] = (f16)a[2]; h[3] = (f16)a[3];
            h[4] = (f16)c[0]; h[5] = (f16)c[1]; h[6] = (f16)c[2]; h[7] = (f16)c[3];
            *(f16x8*)(out + (size_t)(p * 256 + t) * 8) = h;
        }
    } else {
        int idx = (b - 2048) * 256 + threadIdx.x;   // 0 .. 327679
        int c = idx & 1023, img = idx >> 10;
        int np = img >> 5, kt = img & 31;
        int kk = c >> 9, g = (c >> 6) & 7, l = c & 63, r = l & 15, q = l >> 4;
        int col = np * 128 + g * 16 + r;
        int d0  = kt * 64 + kk * 32 + q * 8;
        f16x8 v;
        if (col < NCOLS) {
            int n = col / 11, k = col - n * 11;
            const float* src = W + ((size_t)n * DIM + d0) * 11 + k;
            #pragma unroll
            for (int e = 0; e < 8; ++e) v[e] = (f16)src[(size_t)e * 11];
        } else {
            #pragma unroll
            for (int e = 0; e < 8; ++e) v[e] = (f16)0.f;
        }
        *(f16x8*)(Bf + (size_t)idx * 8) = v;
    }
}

// ---------------------------------------------------------------------------
// GEMM: 256x256 tile, BK=64, 8 waves (2Mx4N, wave-tile 128x64), dbuf 128KB LDS.
// m201-faithful phases: ds_reads at phase TOP (before mid-barrier), MFMA after
// lgkm0. Availability: VM(4) at end of phases B/D establishes the NEXT
// kk-half/tile data one full phase before it is read. vmcnt never 0 in loop.
// Queue trace (loads): entry(kt)=[A1(kt),B1(kt)]; PhA +A0(kt+1); PhB +B0(kt+1),
// VM(4) drains A1,B1(kt); PhC +A1(kt+1); PhD +B1(kt+1), VM(4) drains
// A0,B0(kt+1). MFMA order identical to r8-r10 (bit-identical output).
// ---------------------------------------------------------------------------
__global__ __launch_bounds__(512, 2) void gemm_f16(const f16* __restrict__ Xf,
                                                   const f16* __restrict__ Bf,
                                                   f16* __restrict__ Lh) {
    __shared__ __align__(16) f16 As[2][16384];   // 32 KB per buffer
    __shared__ __align__(16) f16 Bs[2][16384];

    int bid = blockIdx.x;                        // 160 = 8 XCDs * 20
    int swz = (bid & 7) * 20 + (bid >> 3);
    int mt = swz / 5, nt = swz - mt * 5;

    int t = threadIdx.x, w = t >> 6, l = t & 63, r = l & 15, q = l >> 4;
    int wm = w >> 2, wn = w & 3;
    int bpan = (wn >> 1) * 8192, bc4 = (wn & 1) * 4;

    const f16* abase = Xf + (size_t)(mt * 2) * PANEL + (size_t)t * 8;
    const f16* bbase = Bf + (size_t)(nt * 2) * PANEL + (size_t)t * 8;

    f32x4 acc[8][4];
    #pragma unroll
    for (int i = 0; i < 8; ++i)
        #pragma unroll
        for (int j = 0; j < 4; ++j) acc[i][j] = (f32x4)0.f;

    f16x8 af[4], bfr[4];

#define GLD(SRC, DST)                                                            \
    __builtin_amdgcn_global_load_lds(                                            \
        (const __attribute__((address_space(1))) void*)(SRC),                    \
        (__attribute__((address_space(3))) void*)(DST), 16, 0, 0)
    // half-tile (operand, KH): 2 loads (panel0 + panel1), KH = kk slice
#define STAGE_A(KT, C, KH)                                                       \
    { GLD(abase + (size_t)(KT) * IMG + (KH) * 4096, &As[C][(KH) * 4096 + w * 512]);            \
      GLD(abase + PANEL + (size_t)(KT) * IMG + (KH) * 4096, &As[C][(2 + (KH)) * 4096 + w * 512]); }
#define STAGE_B(KT, C, KH)                                                       \
    { GLD(bbase + (size_t)(KT) * IMG + (KH) * 4096, &Bs[C][(KH) * 4096 + w * 512]);            \
      GLD(bbase + PANEL + (size_t)(KT) * IMG + (KH) * 4096, &Bs[C][(2 + (KH)) * 4096 + w * 512]); }
#define DS_AF(C, KK, MH)                                                         \
    { _Pragma("unroll")                                                          \
      for (int m_ = 0; m_ < 4; ++m_)                                             \
          af[m_] = *(const f16x8*)(&As[C][wm * 8192 + (((KK) * 8 + (MH) * 4 + m_) * 64 + l) * 8]); }
#define DS_BF(C, KK)                                                             \
    { _Pragma("unroll")                                                          \
      for (int n_ = 0; n_ < 4; ++n_)                                             \
          bfr[n_] = *(const f16x8*)(&Bs[C][bpan + (((KK) * 8 + bc4 + n_) * 64 + l) * 8]); }
#define MFMA16(MH)                                                               \
    { _Pragma("unroll")                                                          \
      for (int m_ = 0; m_ < 4; ++m_)                                             \
          _Pragma("unroll")                                                      \
          for (int n_ = 0; n_ < 4; ++n_)                                         \
              acc[(MH) * 4 + m_][n_] = __builtin_amdgcn_mfma_f32_16x16x32_f16(   \
                  af[m_], bfr[n_], acc[(MH) * 4 + m_][n_], 0, 0, 0); }
#define BAR __builtin_amdgcn_s_barrier()
#define LGKM0 { asm volatile("s_waitcnt lgkmcnt(0)" ::: "memory");               \
                __builtin_amdgcn_sched_barrier(0); }
#define VM(N) asm volatile("s_waitcnt vmcnt(" #N ")" ::: "memory")
#define PRIO1 __builtin_amdgcn_s_setprio(1)
#define PRIO0 __builtin_amdgcn_s_setprio(0)

#define ITER(KT, CC, CN)                                                         \
    { /* PhA: reads kk0 (avail since prev PhD's VM+BAR) */                       \
      DS_AF(CC, 0, 0) DS_BF(CC, 0)                                               \
      STAGE_A((KT) + 1, CN, 0)                                                   \
      BAR;                                                                       \
      LGKM0 PRIO1; MFMA16(0) PRIO0; BAR;                                         \
      /* PhB: reads kk0/mh1; VM(4) makes kk1(kt) available for PhC */            \
      DS_AF(CC, 0, 1)                                                            \
      STAGE_B((KT) + 1, CN, 0)                                                   \
      VM(4);                                                                     \
      BAR;                                                                       \
      LGKM0 PRIO1; MFMA16(1) PRIO0; BAR;                                         \
      /* PhC: reads kk1 */                                                       \
      DS_AF(CC, 1, 0) DS_BF(CC, 1)                                               \
      STAGE_A((KT) + 1, CN, 1)                                                   \
      BAR;                                                                       \
      LGKM0 PRIO1; MFMA16(0) PRIO0; BAR;                                         \
      /* PhD: reads kk1/mh1; VM(4) makes kk0(kt+1) available for next PhA */     \
      DS_AF(CC, 1, 1)                                                            \
      STAGE_B((KT) + 1, CN, 1)                                                   \
      VM(4);                                                                     \
      BAR;                                                                       \
      LGKM0 PRIO1; MFMA16(1) PRIO0; BAR; }

    // prologue: tile 0 -> buf0, queue order A0,B0,A1,B1 (8 loads);
    // VM(4) drains A0,B0 -> kk0 readable; A1,B1 stay in flight.
    STAGE_A(0, 0, 0) STAGE_B(0, 0, 0) STAGE_A(0, 0, 1) STAGE_B(0, 0, 1)
    VM(4);
    BAR;

    for (int kt = 0; kt < 30; kt += 2) {
        ITER(kt,     0, 1)
        ITER(kt + 1, 1, 0)
    }
    ITER(30, 0, 1)                               // stages tile 31 -> buf 1
    // tail: tile 31 (buf 1); entry outstanding = [A1(31),B1(31)] (4 loads)
    DS_AF(1, 0, 0) DS_BF(1, 0)
    BAR;
    LGKM0 PRIO1; MFMA16(0) PRIO0; BAR;
    DS_AF(1, 0, 1)
    VM(0);                                       // kk1(31) lands
    BAR;
    LGKM0 PRIO1; MFMA16(1) PRIO0; BAR;
    DS_AF(1, 1, 0) DS_BF(1, 1)
    BAR;
    LGKM0 PRIO1; MFMA16(0) PRIO0; BAR;
    DS_AF(1, 1, 1)
    LGKM0 PRIO1; MFMA16(1) PRIO0;

#undef GLD
#undef STAGE_A
#undef STAGE_B
#undef DS_AF
#undef DS_BF
#undef MFMA16
#undef BAR
#undef LGKM0
#undef VM
#undef PRIO1
#undef PRIO0
#undef ITER

    // C write (f16): col = lane&15, row = (lane>>4)*4 + j (verified r1-r10)
    #pragma unroll
    for (int m = 0; m < 8; ++m) {
        int row = mt * 256 + wm * 128 + m * 16 + q * 4;
        #pragma unroll
        for (int n = 0; n < 4; ++n) {
            int col = nt * 256 + wn * 64 + n * 16 + r;
            #pragma unroll
            for (int j = 0; j < 4; ++j)
                Lh[(size_t)(row + j) * NPAD + col] = (f16)acc[m][n][j];
        }
    }
}

// ---------- epilogue: softmax per node (k=11) + 3-level product tree ----------
__global__ void tree_epi(const f16* __restrict__ L, const float* __restrict__ bias,
                         float* __restrict__ out) {
    __shared__ float P[4][NNODES * 11];
    __shared__ f16 R[4][NPAD];
    int w = threadIdx.x >> 6, l = threadIdx.x & 63;
    int row = blockIdx.x * 4 + w;

    const f16x8* src = (const f16x8*)(L + (size_t)row * NPAD);
    f16x8* dst = (f16x8*)R[w];
    dst[l]      = src[l];
    dst[l + 64] = src[l + 64];
    if (l < 32) dst[l + 128] = src[l + 128];

    for (int n = l; n < NNODES; n += 64) {
        float v[11], mx = -1e30f;
        #pragma unroll
        for (int k = 0; k < 11; ++k) { v[k] = (float)R[w][n * 11 + k] + bias[n * 11 + k]; mx = fmaxf(mx, v[k]); }
        float s = 0.f;
        #pragma unroll
        for (int k = 0; k < 11; ++k) { v[k] = __expf(v[k] - mx); s += v[k]; }
        float inv = 1.f / s;
        #pragma unroll
        for (int k = 0; k < 11; ++k) P[w][n * 11 + k] = v[k] * inv;
    }
    __syncthreads();
    const float* Pw = P[w];
    for (int c = l; c < 1000; c += 64) {
        int i  = c / 100;
        int j  = (c % 100) / 10;
        int mm = c % 10;
        float p = Pw[1 + i] * Pw[(1 + i) * 11 + 1 + j] * Pw[(11 + 10 * i + j) * 11 + 1 + mm];
        out[(size_t)row * 1000 + c] = p;
    }
    if (row == 0 && threadIdx.x == 0) out[(size_t)BROWS * 1000] = 0.f;  // penalty
}

extern "C" void kernel_launch(void* const* d_in, const int* in_sizes, int n_in,
                              void* d_out, int out_size, void* d_ws, size_t ws_size,
                              hipStream_t stream) {
    const float* x    = (const float*)d_in[0];
    // d_in[1] = labels (unused)
    const float* W    = (const float*)d_in[2];
    const float* bias = (const float*)d_in[3];
    float* out = (float*)d_out;

    // ws layout:
    //   Xf  f16 fragment-ordered  33,554,432 B
    //   Bf  f16 fragment-ordered   5,242,880 B
    //   Lh  f16 [8192][1280]      20,971,520 B   (total 59,768,832 B)
    f16* Xf = (f16*)d_ws;
    f16* Bf = (f16*)((char*)d_ws + 33554432);
    f16* Lh = (f16*)((char*)d_ws + 38797312);

    prep_all<<<2048 + 1280, 256, 0, stream>>>(x, W, Xf, Bf);
    gemm_f16<<<160, 512, 0, stream>>>(Xf, Bf, Lh);
    tree_epi<<<BROWS / 4, 256, 0, stream>>>(Lh, bias, out);
}

// Round 12
// 97.272 us; speedup vs baseline: 1.0359x; 1.0359x over previous
//
#include <hip/hip_runtime.h>
#include <hip/hip_bf16.h>
#include <hip/hip_fp16.h>

typedef _Float16 f16;
typedef __attribute__((ext_vector_type(8))) _Float16 f16x8;
typedef __attribute__((ext_vector_type(4))) float f32x4;

#define DIM     2048
#define BROWS   8192
#define NCOLS   1221      // 111 nodes * 11
#define NPAD    1280      // 10 panels of 128
#define NNODES  111
#define BK      64
#define NKT     32
#define IMG     8192          // f16 per (128-panel, kt) fragment image (16 KB)
#define PANEL   (32 * IMG)
// Fragment image per (128-panel, kt): 1024 chunks x 16B.
// chunk c = (kk*8 + g)*64 + l ; lane l (r=l&15,q=l>>4) holds
//   row/col = g*16 + r , k = kk*32 + q*8 .. +8.

// ---------------------------------------------------------------------------
// prep_all: block < 2048 -> prep_x (x f32 -> Xf fragment f16)
//           block >= 2048 -> prep_b (W f32 -> Bf fragment f16)
// ---------------------------------------------------------------------------
__global__ __launch_bounds__(256) void prep_all(const float* __restrict__ X,
                                                const float* __restrict__ W,
                                                f16* __restrict__ Xf,
                                                f16* __restrict__ Bf) {
    __shared__ float T[128 * 68];
    int b = blockIdx.x;
    if (b < 2048) {
        int mp = b >> 5, kt = b & 31;
        int t = threadIdx.x;
        int row = t >> 1, half = t & 1;
        const float* src = X + (size_t)(mp * 128 + row) * DIM + kt * 64 + half * 32;
        float* dst = T + row * 68 + half * 32;
        #pragma unroll
        for (int i = 0; i < 8; ++i) ((f32x4*)dst)[i] = ((const f32x4*)src)[i];
        __syncthreads();
        int w = t >> 6, l = t & 63, r = l & 15, q = l >> 4;
        f16* out = Xf + (size_t)b * IMG;
        #pragma unroll
        for (int p = 0; p < 4; ++p) {
            int gk = p * 4 + w;                // = kk*8 + g
            int kk = gk >> 3, g = gk & 7;
            const float* s = T + (g * 16 + r) * 68 + kk * 32 + q * 8;
            f32x4 a = *(const f32x4*)s;
            f32x4 c = *(const f32x4*)(s + 4);
            f16x8 h;
            h[0] = (f16)a[0]; h[1] = (f16)a[1]; h[2] = (f16)a[2]; h[3] = (f16)a[3];
            h[4] = (f16)c[0]; h[5] = (f16)c[1]; h[6] = (f16)c[2]; h[7] = (f16)c[3];
            *(f16x8*)(out + (size_t)(p * 256 + t) * 8) = h;
        }
    } else {
        int idx = (b - 2048) * 256 + threadIdx.x;   // 0 .. 327679
        int c = idx & 1023, img = idx >> 10;
        int np = img >> 5, kt = img & 31;
        int kk = c >> 9, g = (c >> 6) & 7, l = c & 63, r = l & 15, q = l >> 4;
        int col = np * 128 + g * 16 + r;
        int d0  = kt * 64 + kk * 32 + q * 8;
        f16x8 v;
        if (col < NCOLS) {
            int n = col / 11, k = col - n * 11;
            const float* src = W + ((size_t)n * DIM + d0) * 11 + k;
            #pragma unroll
            for (int e = 0; e < 8; ++e) v[e] = (f16)src[(size_t)e * 11];
        } else {
            #pragma unroll
            for (int e = 0; e < 8; ++e) v[e] = (f16)0.f;
        }
        *(f16x8*)(Bf + (size_t)idx * 8) = v;
    }
}

// ---------------------------------------------------------------------------
// GEMM: 128x128 tile, BK=64, 8 waves (wave-tile 64x32) — r4 geometry, but:
//  - B operand: global->VGPR direct (fragment-ordered Bf, per-lane 16B loads),
//    double-buffered in registers. B never touches LDS (-48KB LDS/blk/K-tile).
//  - A operand: global_load_lds into double-buffered LDS (2x16KB).
//  - raw s_barrier + counted vmcnt(6): tile t+1's {4 B-reg + 2 A-lds} loads
//    stay in flight across barriers. vmcnt never 0 in main loop.
// MFMA operand values & order identical to r4 (bit-identical output).
// ---------------------------------------------------------------------------
__global__ __launch_bounds__(512, 4) void gemm_f16(const f16* __restrict__ Xf,
                                                   const f16* __restrict__ Bf,
                                                   f16* __restrict__ Lh) {
    __shared__ __align__(16) f16 As[2][8192];    // 16 KB per buffer

    int bid = blockIdx.x;                        // 640 = 8 XCDs * 80
    int swz = (bid & 7) * 80 + (bid >> 3);
    int mt = swz / 10, nt = swz - mt * 10;

    int t = threadIdx.x, w = t >> 6, l = t & 63, r = l & 15, q = l >> 4;
    int wm = w >> 2, wn = w & 3;                 // 2 x 4 wave grid, tile 64x32

    const f16* abase = Xf + (size_t)mt * PANEL + (size_t)t * 8;
    // B per-lane fragment base: chunk (kk*8 + wn*2 + n), lane l. Offsets from
    // here: kt*8192 + kk*4096 + n*512 (f16 units).
    const f16* bbase = Bf + (size_t)nt * PANEL + (size_t)(wn * 2 * 64 + l) * 8;

    f32x4 acc[4][2];
    #pragma unroll
    for (int i = 0; i < 4; ++i)
        #pragma unroll
        for (int j = 0; j < 2; ++j) acc[i][j] = (f32x4)0.f;

    f16x8 b0[4], b1[4];   // B reg double-buffer: [kk*2+n]

#define LOADB(SET, KT)                                                           \
    { const f16* bp_ = bbase + (size_t)(KT) * 8192;                              \
      SET[0] = *(const f16x8*)(bp_);                                             \
      SET[1] = *(const f16x8*)(bp_ + 512);                                       \
      SET[2] = *(const f16x8*)(bp_ + 4096);                                      \
      SET[3] = *(const f16x8*)(bp_ + 4608); }

#define STAGE_A(KT, C)                                                           \
    { const f16* ap_ = abase + (size_t)(KT) * 8192;                              \
      __builtin_amdgcn_global_load_lds(                                          \
          (const __attribute__((address_space(1))) void*)(ap_),                  \
          (__attribute__((address_space(3))) void*)(&As[C][w * 512]), 16, 0, 0); \
      __builtin_amdgcn_global_load_lds(                                          \
          (const __attribute__((address_space(1))) void*)(ap_ + 4096),           \
          (__attribute__((address_space(3))) void*)(&As[C][4096 + w * 512]), 16, 0, 0); }

#define COMPUTE(C, BS)                                                           \
    { _Pragma("unroll")                                                          \
      for (int kk = 0; kk < 2; ++kk) {                                           \
          f16x8 af[4];                                                           \
          _Pragma("unroll")                                                      \
          for (int m_ = 0; m_ < 4; ++m_)                                         \
              af[m_] = *(const f16x8*)(&As[C][((kk * 8 + wm * 4 + m_) * 64 + l) * 8]); \
          _Pragma("unroll")                                                      \
          for (int m_ = 0; m_ < 4; ++m_)                                         \
              _Pragma("unroll")                                                  \
              for (int n_ = 0; n_ < 2; ++n_)                                     \
                  acc[m_][n_] = __builtin_amdgcn_mfma_f32_16x16x32_f16(          \
                      af[m_], BS[kk * 2 + n_], acc[m_][n_], 0, 0, 0);            \
      } }

#define VM(N)  asm volatile("s_waitcnt vmcnt(" #N ")" ::: "memory")
#define LGKM0  asm volatile("s_waitcnt lgkmcnt(0)" ::: "memory")
#define BAR    __builtin_amdgcn_s_barrier()

    // STEP(kt): entry outstanding = {B(kt)4, A(kt)2}. Issue next tile's 6,
    // drain tile kt with vmcnt(6), barrier, compute, lgkm0+barrier (WAR).
#define STEP(KT, BCUR, BNXT, CC, CN)                                             \
    { LOADB(BNXT, (KT) + 1)                                                      \
      STAGE_A((KT) + 1, CN)                                                      \
      VM(6);                                                                     \
      BAR;                                                                       \
      COMPUTE(CC, BCUR)                                                          \
      LGKM0;                                                                     \
      BAR; }

    // prologue: tile 0 -> {b0, As[0]} (6 loads in flight)
    LOADB(b0, 0)
    STAGE_A(0, 0)

    for (int kt = 0; kt < 30; kt += 2) {
        STEP(kt,     b0, b1, 0, 1)
        STEP(kt + 1, b1, b0, 1, 0)
    }
    STEP(30, b0, b1, 0, 1)                       // prefetches tile 31
    // tail: tile 31; outstanding = {B(31)4, A(31)2}
    VM(0);
    BAR;
    COMPUTE(1, b1)

#undef LOADB
#undef STAGE_A
#undef COMPUTE
#undef VM
#undef LGKM0
#undef BAR
#undef STEP

    // C write (f16): col = lane&15, row = (lane>>4)*4 + j (verified r1-r11)
    #pragma unroll
    for (int m = 0; m < 4; ++m) {
        int row = mt * 128 + wm * 64 + m * 16 + q * 4;
        #pragma unroll
        for (int n = 0; n < 2; ++n) {
            int col = nt * 128 + wn * 32 + n * 16 + r;
            #pragma unroll
            for (int j = 0; j < 4; ++j)
                Lh[(size_t)(row + j) * NPAD + col] = (f16)acc[m][n][j];
        }
    }
}

// ---------- epilogue: softmax per node (k=11) + 3-level product tree ----------
__global__ void tree_epi(const f16* __restrict__ L, const float* __restrict__ bias,
                         float* __restrict__ out) {
    __shared__ float P[4][NNODES * 11];
    __shared__ f16 R[4][NPAD];
    int w = threadIdx.x >> 6, l = threadIdx.x & 63;
    int row = blockIdx.x * 4 + w;

    const f16x8* src = (const f16x8*)(L + (size_t)row * NPAD);
    f16x8* dst = (f16x8*)R[w];
    dst[l]      = src[l];
    dst[l + 64] = src[l + 64];
    if (l < 32) dst[l + 128] = src[l + 128];

    for (int n = l; n < NNODES; n += 64) {
        float v[11], mx = -1e30f;
        #pragma unroll
        for (int k = 0; k < 11; ++k) { v[k] = (float)R[w][n * 11 + k] + bias[n * 11 + k]; mx = fmaxf(mx, v[k]); }
        float s = 0.f;
        #pragma unroll
        for (int k = 0; k < 11; ++k) { v[k] = __expf(v[k] - mx); s += v[k]; }
        float inv = 1.f / s;
        #pragma unroll
        for (int k = 0; k < 11; ++k) P[w][n * 11 + k] = v[k] * inv;
    }
    __syncthreads();
    const float* Pw = P[w];
    for (int c = l; c < 1000; c += 64) {
        int i  = c / 100;
        int j  = (c % 100) / 10;
        int mm = c % 10;
        float p = Pw[1 + i] * Pw[(1 + i) * 11 + 1 + j] * Pw[(11 + 10 * i + j) * 11 + 1 + mm];
        out[(size_t)row * 1000 + c] = p;
    }
    if (row == 0 && threadIdx.x == 0) out[(size_t)BROWS * 1000] = 0.f;  // penalty
}

extern "C" void kernel_launch(void* const* d_in, const int* in_sizes, int n_in,
                              void* d_out, int out_size, void* d_ws, size_t ws_size,
                              hipStream_t stream) {
    const float* x    = (const float*)d_in[0];
    // d_in[1] = labels (unused)
    const float* W    = (const float*)d_in[2];
    const float* bias = (const float*)d_in[3];
    float* out = (float*)d_out;

    // ws layout:
    //   Xf  f16 fragment-ordered  33,554,432 B
    //   Bf  f16 fragment-ordered   5,242,880 B
    //   Lh  f16 [8192][1280]      20,971,520 B   (total 59,768,832 B)
    f16* Xf = (f16*)d_ws;
    f16* Bf = (f16*)((char*)d_ws + 33554432);
    f16* Lh = (f16*)((char*)d_ws + 38797312);

    prep_all<<<2048 + 1280, 256, 0, stream>>>(x, W, Xf, Bf);
    gemm_f16<<<640, 512, 0, stream>>>(Xf, Bf, Lh);
    tree_epi<<<BROWS / 4, 256, 0, stream>>>(Lh, bias, out);
}